// Round 4
// baseline (1363.932 us; speedup 1.0000x reference)
//
#include <hip/hip_runtime.h>

#define KPTS 128
#define NB 16

__global__ __launch_bounds__(256) void miniemb_kernel(
    const float* __restrict__ windows,
    const float* __restrict__ W1, const float* __restrict__ b1,
    const float* __restrict__ W2, const float* __restrict__ b2,
    const float* __restrict__ W3, const float* __restrict__ b3,
    float* __restrict__ out)
{
    __shared__ float pts[KPTS][3];
    __shared__ float sq[KPTS];
    __shared__ float rel[KPTS][NB][3];   // normalized relative coords

    const int m = blockIdx.x;
    const int tid = threadIdx.x;

    // ---- stage points ----
    const float* wm = windows + (size_t)m * KPTS * 3;
    for (int i = tid; i < KPTS * 3; i += 256) ((float*)pts)[i] = wm[i];
    __syncthreads();
    if (tid < KPTS) {
        float x = pts[tid][0], y = pts[tid][1], z = pts[tid][2];
        // np.sum(w*w,-1): individually rounded products, sequential sum, NO fma
        sq[tid] = __fadd_rn(__fadd_rn(__fmul_rn(x, x), __fmul_rn(y, y)),
                            __fmul_rn(z, z));
    }
    __syncthreads();

    // ---- kNN (thread per point), np-bit-exact fp32 distances,
    //      selection stable under EXACT ties (lower index wins, like top_k) ----
    if (tid < KPTS) {
        const int k = tid;
        const float qx = pts[k][0], qy = pts[k][1], qz = pts[k][2];
        const float qs = sq[k];
        float bd[NB];
        int   bi[NB];
        #pragma unroll
        for (int t = 0; t < NB; ++t) { bd[t] = 3.0e38f; bi[t] = 0x7fffffff; }
        #pragma unroll 1
        for (int j = 0; j < KPTS; ++j) {
            // np einsum inner loop: rounded products, sequential adds, NO fma
            float dot = __fadd_rn(__fadd_rn(__fmul_rn(qx, pts[j][0]),
                                            __fmul_rn(qy, pts[j][1])),
                                  __fmul_rn(qz, pts[j][2]));
            // d2 = (sq_k + sq_j) - 2*dot   (2*dot exact; one rounded subtract)
            float dd = __fsub_rn(__fadd_rn(qs, sq[j]), __fmul_rn(2.0f, dot));
            int   ii = j;
            // lexicographic (value, index) insertion: stable under exact ties,
            // including the displaced-carrier-past-equal case
            #pragma unroll
            for (int t = 0; t < NB; ++t) {
                bool sw = (dd < bd[t]) || ((dd == bd[t]) && (ii < bi[t]));
                float nf = sw ? dd : bd[t];
                float xf = sw ? bd[t] : dd;
                int   ni = sw ? ii : bi[t];
                int   xi = sw ? bi[t] : ii;
                bd[t] = nf; bi[t] = ni;
                dd = xf; ii = xi;
            }
        }
        // relative coords + neighborhood scale (continuous -> fp32 fine)
        float rx[NB], ry[NB], rz[NB];
        float scale = 0.0f;
        #pragma unroll
        for (int t = 0; t < NB; ++t) {
            int j = bi[t];
            float dx = pts[j][0] - qx;
            float dy = pts[j][1] - qy;
            float dz = pts[j][2] - qz;
            rx[t] = dx; ry[t] = dy; rz[t] = dz;
            scale = fmaxf(scale, sqrtf(dx * dx + dy * dy + dz * dz));
        }
        scale = fmaxf(scale, 1e-8f);
        float inv = 1.0f / scale;
        #pragma unroll
        for (int t = 0; t < NB; ++t) {
            rel[k][t][0] = rx[t] * inv;
            rel[k][t][1] = ry[t] * inv;
            rel[k][t][2] = rz[t] * inv;
        }
    }
    __syncthreads();

    // ---- MLP: thread = (point, neighbor); 16 points x 16 neighbors per chunk ----
    const int p_lo  = tid >> 4;   // 0..15
    const int nlane = tid & 15;   // neighbor id == lane%16

    float b3r[8];
    #pragma unroll
    for (int cg = 0; cg < 8; ++cg) b3r[cg] = b3[cg * 16 + nlane];

    #pragma unroll 1
    for (int chunk = 0; chunk < 8; ++chunk) {
        const int p = chunk * 16 + p_lo;
        const float r0 = rel[p][nlane][0];
        const float r1 = rel[p][nlane][1];
        const float r2 = rel[p][nlane][2];

        // layer 1: 3 -> 32, relu   (weights wave-uniform -> scalar loads)
        float h1[32];
        #pragma unroll
        for (int o = 0; o < 32; ++o) {
            float t = fmaf(r0, W1[o], b1[o]);
            t = fmaf(r1, W1[32 + o], t);
            t = fmaf(r2, W1[64 + o], t);
            h1[o] = fmaxf(t, 0.0f);
        }

        // layer 2: 32 -> 64, relu
        float h2[64];
        #pragma unroll
        for (int o = 0; o < 64; ++o) h2[o] = b2[o];
        #pragma unroll
        for (int i = 0; i < 32; ++i) {
            const float hv = h1[i];
            #pragma unroll
            for (int o = 0; o < 64; ++o)
                h2[o] = fmaf(hv, W2[i * 64 + o], h2[o]);
        }
        #pragma unroll
        for (int o = 0; o < 64; ++o) h2[o] = fmaxf(h2[o], 0.0f);

        // layer 3: 64 -> 128 in channel-groups of 16, max-pool over 16 neighbor lanes
        float* outp = out + (((size_t)m * KPTS + p) << 7);
        #pragma unroll 1
        for (int cg = 0; cg < 8; ++cg) {
            float acc[16];
            #pragma unroll
            for (int ci = 0; ci < 16; ++ci) acc[ci] = 0.0f;
            #pragma unroll
            for (int j = 0; j < 64; ++j) {
                const float hj = h2[j];
                #pragma unroll
                for (int ci = 0; ci < 16; ++ci)
                    acc[ci] = fmaf(hj, W3[j * 128 + cg * 16 + ci], acc[ci]);
            }
            float sel = 0.0f;
            #pragma unroll
            for (int ci = 0; ci < 16; ++ci) {
                float v = acc[ci];
                v = fmaxf(v, __shfl_xor(v, 1));
                v = fmaxf(v, __shfl_xor(v, 2));
                v = fmaxf(v, __shfl_xor(v, 4));
                v = fmaxf(v, __shfl_xor(v, 8));
                if (ci == nlane) sel = v;   // lane keeps its own channel
            }
            outp[cg * 16 + nlane] = sel + b3r[cg];
        }
    }
}

extern "C" void kernel_launch(void* const* d_in, const int* in_sizes, int n_in,
                              void* d_out, int out_size, void* d_ws, size_t ws_size,
                              hipStream_t stream) {
    const float* windows = (const float*)d_in[0];
    const float* W1 = (const float*)d_in[1];
    const float* b1 = (const float*)d_in[2];
    const float* W2 = (const float*)d_in[3];
    const float* b2 = (const float*)d_in[4];
    const float* W3 = (const float*)d_in[5];
    const float* b3 = (const float*)d_in[6];
    float* out = (float*)d_out;
    hipLaunchKernelGGL(miniemb_kernel, dim3(1024), dim3(256), 0, stream,
                       windows, W1, b1, W2, b2, W3, b3, out);
}

// Round 5
// 677.009 us; speedup vs baseline: 2.0146x; 2.0146x over previous
//
#include <hip/hip_runtime.h>

#define KPTS 128
#define NB 16

typedef __bf16 bf16x8 __attribute__((ext_vector_type(8)));
typedef float  f32x4  __attribute__((ext_vector_type(4)));

#define MFMA(a, b, c) __builtin_amdgcn_mfma_f32_16x16x32_bf16((a), (b), (c), 0, 0, 0)

// pack fp32 -> (hi bf16, lo bf16) in one u32:  v ~= hi + lo, lo error ~2^-17*v
static __device__ __forceinline__ unsigned pack2(float v) {
    __bf16 hi = (__bf16)v;
    __bf16 lo = (__bf16)(v - (float)hi);
    return (unsigned)__builtin_bit_cast(unsigned short, hi)
         | ((unsigned)__builtin_bit_cast(unsigned short, lo) << 16);
}

__global__ __launch_bounds__(256) void miniemb_kernel(
    const float* __restrict__ windows,
    const float* __restrict__ W1, const float* __restrict__ b1,
    const float* __restrict__ W2, const float* __restrict__ b2,
    const float* __restrict__ W3, const float* __restrict__ b3,
    float* __restrict__ out)
{
    __shared__ float pts[KPTS][3];
    __shared__ float sq[KPTS];
    __shared__ float rel[KPTS][NB][3];     // normalized relative coords
    __shared__ unsigned h2p[4][NB][68];    // per-wave h2 staging: (hi|lo<<16) bf16 pair

    const int m    = blockIdx.x;
    const int tid  = threadIdx.x;
    const int w    = tid >> 6;     // wave id 0..3
    const int lane = tid & 63;
    const int g    = lane >> 4;    // lane quad 0..3
    const int ln   = lane & 15;

    // ---- persistent weight fragments / per-lane weights (once per block) ----
    // B-frag layout (16x16x32): lane holds B[k = g*8+j][n = tile*16+ln], j=0..7
    bf16x8 w2f[4];
    #pragma unroll
    for (int t = 0; t < 4; ++t) {
        #pragma unroll
        for (int j = 0; j < 8; ++j)
            w2f[t][j] = (__bf16)W2[(g * 8 + j) * 64 + t * 16 + ln];
    }
    bf16x8 w3f[16];   // [n*2+kb]
    #pragma unroll
    for (int n = 0; n < 8; ++n) {
        #pragma unroll
        for (int kb = 0; kb < 2; ++kb) {
            #pragma unroll
            for (int j = 0; j < 8; ++j)
                w3f[n * 2 + kb][j] =
                    (__bf16)W3[(kb * 32 + g * 8 + j) * 128 + n * 16 + ln];
        }
    }
    float w1r0[8], w1r1[8], w1r2[8], b1r[8];   // L1 channels c = g*8+j (fp32)
    #pragma unroll
    for (int j = 0; j < 8; ++j) {
        const int c = g * 8 + j;
        w1r0[j] = W1[c]; w1r1[j] = W1[32 + c]; w1r2[j] = W1[64 + c]; b1r[j] = b1[c];
    }
    float b2r[4];
    #pragma unroll
    for (int t = 0; t < 4; ++t) b2r[t] = b2[t * 16 + ln];
    const float b3r0 = b3[(2 * g) * 16 + ln];
    const float b3r1 = b3[(2 * g + 1) * 16 + ln];

    // ---- stage points ----
    const float* wm = windows + (size_t)m * KPTS * 3;
    for (int i = tid; i < KPTS * 3; i += 256) ((float*)pts)[i] = wm[i];
    __syncthreads();
    if (tid < KPTS) {
        float x = pts[tid][0], y = pts[tid][1], z = pts[tid][2];
        sq[tid] = __fadd_rn(__fadd_rn(__fmul_rn(x, x), __fmul_rn(y, y)),
                            __fmul_rn(z, z));
    }
    __syncthreads();

    // ---- kNN (bit-proven round-4 path: np-exact fp32 + lexicographic ties) ----
    if (tid < KPTS) {
        const int k = tid;
        const float qx = pts[k][0], qy = pts[k][1], qz = pts[k][2];
        const float qs = sq[k];
        float bd[NB];
        int   bi[NB];
        #pragma unroll
        for (int t = 0; t < NB; ++t) { bd[t] = 3.0e38f; bi[t] = 0x7fffffff; }
        #pragma unroll 1
        for (int j = 0; j < KPTS; ++j) {
            float dot = __fadd_rn(__fadd_rn(__fmul_rn(qx, pts[j][0]),
                                            __fmul_rn(qy, pts[j][1])),
                                  __fmul_rn(qz, pts[j][2]));
            float dd = __fsub_rn(__fadd_rn(qs, sq[j]), __fmul_rn(2.0f, dot));
            int   ii = j;
            #pragma unroll
            for (int t = 0; t < NB; ++t) {
                bool sw = (dd < bd[t]) || ((dd == bd[t]) && (ii < bi[t]));
                float nf = sw ? dd : bd[t];
                float xf = sw ? bd[t] : dd;
                int   ni = sw ? ii : bi[t];
                int   xi = sw ? bi[t] : ii;
                bd[t] = nf; bi[t] = ni;
                dd = xf; ii = xi;
            }
        }
        float rx[NB], ry[NB], rz[NB];
        float scale = 0.0f;
        #pragma unroll
        for (int t = 0; t < NB; ++t) {
            int j = bi[t];
            float dx = pts[j][0] - qx;
            float dy = pts[j][1] - qy;
            float dz = pts[j][2] - qz;
            rx[t] = dx; ry[t] = dy; rz[t] = dz;
            scale = fmaxf(scale, sqrtf(dx * dx + dy * dy + dz * dz));
        }
        scale = fmaxf(scale, 1e-8f);
        float inv = 1.0f / scale;
        #pragma unroll
        for (int t = 0; t < NB; ++t) {
            rel[k][t][0] = rx[t] * inv;
            rel[k][t][1] = ry[t] * inv;
            rel[k][t][2] = rz[t] * inv;
        }
    }
    __syncthreads();

    // ---- MFMA MLP: wave w handles points w*32 .. w*32+31, one point per step ----
    #pragma unroll 1
    for (int i = 0; i < 32; ++i) {
        const int p = w * 32 + i;

        // L1 (fp32 VALU) straight into A-frag layout: lane = neighbor ln,
        // channels k = g*8+j. Activation split hi/lo.
        const float r0 = rel[p][ln][0];
        const float r1 = rel[p][ln][1];
        const float r2 = rel[p][ln][2];
        bf16x8 a1hi, a1lo;
        #pragma unroll
        for (int j = 0; j < 8; ++j) {
            float h = fmaf(r2, w1r2[j], fmaf(r1, w1r1[j], fmaf(r0, w1r0[j], b1r[j])));
            h = fmaxf(h, 0.0f);
            __bf16 hi = (__bf16)h;
            a1hi[j] = hi;
            a1lo[j] = (__bf16)(h - (float)hi);
        }

        // L2: 4 N-tiles of 16x16x32 MFMA (A-split => 2 mfma/tile)
        f32x4 c2[4];
        #pragma unroll
        for (int t = 0; t < 4; ++t) {
            f32x4 acc = {0.0f, 0.0f, 0.0f, 0.0f};
            acc = MFMA(a1hi, w2f[t], acc);
            acc = MFMA(a1lo, w2f[t], acc);
            c2[t] = acc;
        }
        // epilogue: +b2, relu, hi/lo pack -> per-wave LDS (C layout: row g*4+r = nb)
        #pragma unroll
        for (int t = 0; t < 4; ++t) {
            #pragma unroll
            for (int r = 0; r < 4; ++r) {
                float v = fmaxf(c2[t][r] + b2r[t], 0.0f);
                h2p[w][g * 4 + r][t * 16 + ln] = pack2(v);
            }
        }

        // A3 fragments: lane = neighbor ln, k = kb*32 + g*8 + j
        const unsigned* row = &h2p[w][ln][0];
        uint4 q0 = *(const uint4*)(row + g * 8);
        uint4 q1 = *(const uint4*)(row + g * 8 + 4);
        uint4 q2 = *(const uint4*)(row + 32 + g * 8);
        uint4 q3 = *(const uint4*)(row + 32 + g * 8 + 4);
        unsigned pk0[8] = {q0.x, q0.y, q0.z, q0.w, q1.x, q1.y, q1.z, q1.w};
        unsigned pk1[8] = {q2.x, q2.y, q2.z, q2.w, q3.x, q3.y, q3.z, q3.w};
        bf16x8 hi0, lo0, hi1, lo1;
        #pragma unroll
        for (int j = 0; j < 8; ++j) {
            hi0[j] = __builtin_bit_cast(__bf16, (unsigned short)(pk0[j] & 0xffffu));
            lo0[j] = __builtin_bit_cast(__bf16, (unsigned short)(pk0[j] >> 16));
            hi1[j] = __builtin_bit_cast(__bf16, (unsigned short)(pk1[j] & 0xffffu));
            lo1[j] = __builtin_bit_cast(__bf16, (unsigned short)(pk1[j] >> 16));
        }

        // L3: 8 N-tiles x (2 kb) x (hi/lo) MFMA, then max over 16 neighbors
        float tm[8];
        #pragma unroll
        for (int n = 0; n < 8; ++n) {
            f32x4 acc = {0.0f, 0.0f, 0.0f, 0.0f};
            acc = MFMA(hi0, w3f[n * 2 + 0], acc);
            acc = MFMA(hi1, w3f[n * 2 + 1], acc);
            acc = MFMA(lo0, w3f[n * 2 + 0], acc);
            acc = MFMA(lo1, w3f[n * 2 + 1], acc);
            float v = fmaxf(fmaxf(acc[0], acc[1]), fmaxf(acc[2], acc[3]));
            v = fmaxf(v, __shfl_xor(v, 16));
            v = fmaxf(v, __shfl_xor(v, 32));
            tm[n] = v;   // all lanes now hold tile-n max for channel (n*16+ln)
        }
        // lane quad g stores tiles 2g, 2g+1 -> wave covers 512B contiguous
        float s0 = tm[0], s1 = tm[1];
        if (g == 1) { s0 = tm[2]; s1 = tm[3]; }
        if (g == 2) { s0 = tm[4]; s1 = tm[5]; }
        if (g == 3) { s0 = tm[6]; s1 = tm[7]; }
        float* outp = out + ((size_t)(m * KPTS + p) << 7);
        outp[(2 * g) * 16 + ln]     = s0 + b3r0;
        outp[(2 * g + 1) * 16 + ln] = s1 + b3r1;
    }
}

extern "C" void kernel_launch(void* const* d_in, const int* in_sizes, int n_in,
                              void* d_out, int out_size, void* d_ws, size_t ws_size,
                              hipStream_t stream) {
    const float* windows = (const float*)d_in[0];
    const float* W1 = (const float*)d_in[1];
    const float* b1 = (const float*)d_in[2];
    const float* W2 = (const float*)d_in[3];
    const float* b2 = (const float*)d_in[4];
    const float* W3 = (const float*)d_in[5];
    const float* b3 = (const float*)d_in[6];
    float* out = (float*)d_out;
    hipLaunchKernelGGL(miniemb_kernel, dim3(1024), dim3(256), 0, stream,
                       windows, W1, b1, W2, b2, W3, b3, out);
}

// Round 6
// 406.420 us; speedup vs baseline: 3.3560x; 1.6658x over previous
//
#include <hip/hip_runtime.h>

#define KPTS 128
#define NB 16

typedef __bf16 bf16x8 __attribute__((ext_vector_type(8)));
typedef float  f32x4  __attribute__((ext_vector_type(4)));

#define MFMA(a, b, c) __builtin_amdgcn_mfma_f32_16x16x32_bf16((a), (b), (c), 0, 0, 0)

__global__ __launch_bounds__(256) void miniemb_kernel(
    const float* __restrict__ windows,
    const float* __restrict__ W1, const float* __restrict__ b1,
    const float* __restrict__ W2, const float* __restrict__ b2,
    const float* __restrict__ W3, const float* __restrict__ b3,
    float* __restrict__ out)
{
    __shared__ float pts[KPTS][3];
    __shared__ float sq[KPTS];
    __shared__ float rel[KPTS][NB][3];   // normalized relative coords
    __shared__ uint4 w3lds[16][64];      // W3 B-frags: [frag = n*2+kb][lane]

    const int m    = blockIdx.x;
    const int tid  = threadIdx.x;
    const int w    = tid >> 6;     // wave id 0..3
    const int lane = tid & 63;
    const int g    = lane >> 4;    // lane quad
    const int ln   = lane & 15;

    // ---- persistent per-lane weights ----
    // sigma: logical h2-channel c = kb*32+8q+j  <->  physical (tile 2kb+(j>>2), row 4q+(j&3)).
    // With this map, D2^T leaves each lane holding exactly its L3 A-frag channels.
    // W2^T as A-frag: lane ln = physical row, k-slot g*8+j = input (h1) channel.
    bf16x8 w2A[4];
    #pragma unroll
    for (int t = 0; t < 4; ++t) {
        const int c = 32 * (t >> 1) + 8 * (ln >> 2) + 4 * (t & 1) + (ln & 3); // sigma^-1(t, ln)
        #pragma unroll
        for (int j = 0; j < 8; ++j)
            w2A[t][j] = (__bf16)W2[(g * 8 + j) * 64 + c];
    }
    float b2p[16];                      // b2 permuted to C2^T positions (t, 4g+r)
    #pragma unroll
    for (int t = 0; t < 4; ++t)
        #pragma unroll
        for (int r = 0; r < 4; ++r)
            b2p[t * 4 + r] = b2[32 * (t >> 1) + 8 * g + 4 * (t & 1) + r];

    float w1r0[8], w1r1[8], w1r2[8], b1r[8];   // L1 fp32 weights, channels g*8+j
    #pragma unroll
    for (int j = 0; j < 8; ++j) {
        const int c = g * 8 + j;
        w1r0[j] = W1[c]; w1r1[j] = W1[32 + c]; w1r2[j] = W1[64 + c]; b1r[j] = b1[c];
    }
    const float b3r0 = b3[(2 * g) * 16 + ln];
    const float b3r1 = b3[(2 * g + 1) * 16 + ln];

    // ---- stage points ----
    const float* wm = windows + (size_t)m * KPTS * 3;
    for (int i = tid; i < KPTS * 3; i += 256) ((float*)pts)[i] = wm[i];
    __syncthreads();
    if (tid < KPTS) {
        float x = pts[tid][0], y = pts[tid][1], z = pts[tid][2];
        sq[tid] = __fadd_rn(__fadd_rn(__fmul_rn(x, x), __fmul_rn(y, y)),
                            __fmul_rn(z, z));
    }
    __syncthreads();

    if (tid < KPTS) {
        // ---- kNN (bit-proven: np-exact fp32 + lexicographic tie-break) ----
        const int k = tid;
        const float qx = pts[k][0], qy = pts[k][1], qz = pts[k][2];
        const float qs = sq[k];
        float bd[NB];
        int   bi[NB];
        #pragma unroll
        for (int t = 0; t < NB; ++t) { bd[t] = 3.0e38f; bi[t] = 0x7fffffff; }
        #pragma unroll 1
        for (int j = 0; j < KPTS; ++j) {
            float dot = __fadd_rn(__fadd_rn(__fmul_rn(qx, pts[j][0]),
                                            __fmul_rn(qy, pts[j][1])),
                                  __fmul_rn(qz, pts[j][2]));
            float dd = __fsub_rn(__fadd_rn(qs, sq[j]), __fmul_rn(2.0f, dot));
            int   ii = j;
            #pragma unroll
            for (int t = 0; t < NB; ++t) {
                bool sw = (dd < bd[t]) || ((dd == bd[t]) && (ii < bi[t]));
                float nf = sw ? dd : bd[t];
                float xf = sw ? bd[t] : dd;
                int   ni = sw ? ii : bi[t];
                int   xi = sw ? bi[t] : ii;
                bd[t] = nf; bi[t] = ni;
                dd = xf; ii = xi;
            }
        }
        float rx[NB], ry[NB], rz[NB];
        float scale = 0.0f;
        #pragma unroll
        for (int t = 0; t < NB; ++t) {
            int j = bi[t];
            float dx = pts[j][0] - qx;
            float dy = pts[j][1] - qy;
            float dz = pts[j][2] - qz;
            rx[t] = dx; ry[t] = dy; rz[t] = dz;
            scale = fmaxf(scale, sqrtf(dx * dx + dy * dy + dz * dz));
        }
        scale = fmaxf(scale, 1e-8f);
        float inv = 1.0f / scale;
        #pragma unroll
        for (int t = 0; t < NB; ++t) {
            rel[k][t][0] = rx[t] * inv;
            rel[k][t][1] = ry[t] * inv;
            rel[k][t][2] = rz[t] * inv;
        }
    } else {
        // ---- waves 2,3: fill W3 fragment LDS concurrently with kNN ----
        const int f0 = (w - 2) * 8;
        #pragma unroll
        for (int q = 0; q < 8; ++q) {
            const int f = f0 + q, n = f >> 1, kb = f & 1;
            bf16x8 v;
            #pragma unroll
            for (int j = 0; j < 8; ++j)
                v[j] = (__bf16)W3[(kb * 32 + g * 8 + j) * 128 + n * 16 + ln];
            w3lds[f][lane] = __builtin_bit_cast(uint4, v);
        }
    }
    __syncthreads();

    // ---- MFMA MLP: wave w handles points w*32 .. w*32+31 ----
    #pragma unroll 1
    for (int i = 0; i < 32; ++i) {
        const int p = w * 32 + i;

        // L1 (fp32 VALU) into B-frag layout: lane=neighbor ln, k = g*8+j, hi/lo split
        const float r0 = rel[p][ln][0];
        const float r1 = rel[p][ln][1];
        const float r2 = rel[p][ln][2];
        bf16x8 a1hi, a1lo;
        #pragma unroll
        for (int j = 0; j < 8; ++j) {
            float h = fmaf(r2, w1r2[j], fmaf(r1, w1r1[j], fmaf(r0, w1r0[j], b1r[j])));
            h = fmaxf(h, 0.0f);
            __bf16 hi = (__bf16)h;
            a1hi[j] = hi;
            a1lo[j] = (__bf16)(h - (float)hi);
        }

        // L2 transposed: D2^T = W2^T(A) * h1^T(B), bias via C-init
        f32x4 c2[4];
        #pragma unroll
        for (int t = 0; t < 4; ++t) {
            f32x4 acc = {b2p[t * 4 + 0], b2p[t * 4 + 1], b2p[t * 4 + 2], b2p[t * 4 + 3]};
            acc = MFMA(w2A[t], a1hi, acc);
            acc = MFMA(w2A[t], a1lo, acc);
            c2[t] = acc;
        }

        // relu + hi/lo pack straight into L3 A-frags (pure register renaming via sigma)
        bf16x8 a3hi0, a3lo0, a3hi1, a3lo1;
        #pragma unroll
        for (int j = 0; j < 8; ++j) {
            const int r = j & 3;
            {   // kb=0: tiles 0,1
                const int t = (j >> 2);
                float v = fmaxf(c2[t][r], 0.0f);
                __bf16 hi = (__bf16)v;
                a3hi0[j] = hi; a3lo0[j] = (__bf16)(v - (float)hi);
            }
            {   // kb=1: tiles 2,3
                const int t = 2 + (j >> 2);
                float v = fmaxf(c2[t][r], 0.0f);
                __bf16 hi = (__bf16)v;
                a3hi1[j] = hi; a3lo1[j] = (__bf16)(v - (float)hi);
            }
        }

        // L3: stream W3 frags from LDS, 2 n-tiles per step, software-pipelined
        float tm[8];
        uint4 c0a = w3lds[0][lane], c0b = w3lds[1][lane];
        uint4 c1a = w3lds[2][lane], c1b = w3lds[3][lane];
        #pragma unroll
        for (int nn = 0; nn < 4; ++nn) {
            uint4 n0a, n0b, n1a, n1b;
            if (nn < 3) {
                n0a = w3lds[nn * 4 + 4][lane]; n0b = w3lds[nn * 4 + 5][lane];
                n1a = w3lds[nn * 4 + 6][lane]; n1b = w3lds[nn * 4 + 7][lane];
            }
            f32x4 acc0 = {0.0f, 0.0f, 0.0f, 0.0f};
            f32x4 acc1 = {0.0f, 0.0f, 0.0f, 0.0f};
            acc0 = MFMA(a3hi0, __builtin_bit_cast(bf16x8, c0a), acc0);
            acc0 = MFMA(a3hi1, __builtin_bit_cast(bf16x8, c0b), acc0);
            acc0 = MFMA(a3lo0, __builtin_bit_cast(bf16x8, c0a), acc0);
            acc0 = MFMA(a3lo1, __builtin_bit_cast(bf16x8, c0b), acc0);
            acc1 = MFMA(a3hi0, __builtin_bit_cast(bf16x8, c1a), acc1);
            acc1 = MFMA(a3hi1, __builtin_bit_cast(bf16x8, c1b), acc1);
            acc1 = MFMA(a3lo0, __builtin_bit_cast(bf16x8, c1a), acc1);
            acc1 = MFMA(a3lo1, __builtin_bit_cast(bf16x8, c1b), acc1);
            float v0 = fmaxf(fmaxf(acc0[0], acc0[1]), fmaxf(acc0[2], acc0[3]));
            v0 = fmaxf(v0, __shfl_xor(v0, 16));
            v0 = fmaxf(v0, __shfl_xor(v0, 32));
            tm[nn * 2] = v0;
            float v1 = fmaxf(fmaxf(acc1[0], acc1[1]), fmaxf(acc1[2], acc1[3]));
            v1 = fmaxf(v1, __shfl_xor(v1, 16));
            v1 = fmaxf(v1, __shfl_xor(v1, 32));
            tm[nn * 2 + 1] = v1;
            c0a = n0a; c0b = n0b; c1a = n1a; c1b = n1b;
        }

        // lane quad g stores channel tiles 2g, 2g+1
        float s0 = tm[0], s1 = tm[1];
        if (g == 1) { s0 = tm[2]; s1 = tm[3]; }
        if (g == 2) { s0 = tm[4]; s1 = tm[5]; }
        if (g == 3) { s0 = tm[6]; s1 = tm[7]; }
        float* outp = out + ((size_t)(m * KPTS + p) << 7);
        outp[(2 * g) * 16 + ln]     = s0 + b3r0;
        outp[(2 * g + 1) * 16 + ln] = s1 + b3r1;
    }
}

extern "C" void kernel_launch(void* const* d_in, const int* in_sizes, int n_in,
                              void* d_out, int out_size, void* d_ws, size_t ws_size,
                              hipStream_t stream) {
    const float* windows = (const float*)d_in[0];
    const float* W1 = (const float*)d_in[1];
    const float* b1 = (const float*)d_in[2];
    const float* W2 = (const float*)d_in[3];
    const float* b2 = (const float*)d_in[4];
    const float* W3 = (const float*)d_in[5];
    const float* b3 = (const float*)d_in[6];
    float* out = (float*)d_out;
    hipLaunchKernelGGL(miniemb_kernel, dim3(1024), dim3(256), 0, stream,
                       windows, W1, b1, W2, b2, W3, b3, out);
}

// Round 7
// 232.478 us; speedup vs baseline: 5.8669x; 1.7482x over previous
//
#include <hip/hip_runtime.h>

typedef __bf16 bf16x8 __attribute__((ext_vector_type(8)));
typedef float  f32x4  __attribute__((ext_vector_type(4)));
typedef unsigned long long u64;

#define MFMA(a, b, c) __builtin_amdgcn_mfma_f32_16x16x32_bf16((a), (b), (c), 0, 0, 0)

__global__ __launch_bounds__(256) void miniemb_kernel(
    const float* __restrict__ windows,
    const float* __restrict__ W1, const float* __restrict__ b1,
    const float* __restrict__ W2, const float* __restrict__ b2,
    const float* __restrict__ W3, const float* __restrict__ b3,
    float* __restrict__ out)
{
    __shared__ float pts4[128][4];   // x,y,z,sq  (b128 per candidate)
    __shared__ u64   uni[128][32];   // per point 256B: kNN lists, then rel[16][3] f32
    __shared__ uint4 w3lds[16][64];  // W3 B-frags [frag = n*2+kb][lane]

    const int m    = blockIdx.x;
    const int tid  = threadIdx.x;
    const int w    = tid >> 6;
    const int lane = tid & 63;
    const int g    = lane >> 4;
    const int ln   = lane & 15;

    // ---- phase 0: fill w3lds (all waves) + stage pts4 ----
    #pragma unroll
    for (int q = 0; q < 4; ++q) {
        const int f = w * 4 + q, n = f >> 1, kb = f & 1;
        bf16x8 v;
        #pragma unroll
        for (int j = 0; j < 8; ++j)
            v[j] = (__bf16)W3[(kb * 32 + g * 8 + j) * 128 + n * 16 + ln];
        w3lds[f][lane] = __builtin_bit_cast(uint4, v);
    }
    const float* wm = windows + (size_t)m * 128 * 3;
    if (tid < 128) {
        float x = wm[tid * 3], y = wm[tid * 3 + 1], z = wm[tid * 3 + 2];
        float s = __fadd_rn(__fadd_rn(__fmul_rn(x, x), __fmul_rn(y, y)),
                            __fmul_rn(z, z));
        f32x4 P = {x, y, z, s};
        *(f32x4*)&pts4[tid][0] = P;
    }
    __syncthreads();

    // ---- phase 1: kNN scan, 2 threads per point, u64 sortable keys ----
    const int k   = tid >> 1;      // point
    const int h   = tid & 1;       // half
    const int ksw = k & 7;         // bank swizzle
    f32x4 Q = *(const f32x4*)&pts4[k][0];
    {
        u64 bd[16];
        #pragma unroll
        for (int t = 0; t < 16; ++t) bd[t] = ~0ull;
        #pragma unroll 1
        for (int jj = 0; jj < 64; ++jj) {
            const int j = (h << 6) + jj;
            f32x4 P = *(const f32x4*)&pts4[j][0];
            // np-exact d2 (bit-identical to the round-4 proven path)
            float dot = __fadd_rn(__fadd_rn(__fmul_rn(Q.x, P.x),
                                            __fmul_rn(Q.y, P.y)),
                                  __fmul_rn(Q.z, P.z));
            float dd = __fsub_rn(__fadd_rn(Q.w, P.w), __fmul_rn(2.0f, dot));
            unsigned u = __float_as_uint(dd);
            unsigned key32 = u ^ (((unsigned)(((int)u) >> 31)) | 0x80000000u);
            u64 kk = ((u64)key32 << 32) | (unsigned)j;
            #pragma unroll
            for (int t = 0; t < 16; ++t) {
                bool sw = kk < bd[t];
                u64 mn = sw ? kk : bd[t];
                u64 mx = sw ? bd[t] : kk;
                bd[t] = mn; kk = mx;
            }
        }
        // write sorted 16-list (pairs, bank-swizzled)
        #pragma unroll
        for (int q = 0; q < 8; ++q) {
            uint4 val = { (unsigned)bd[2 * q],     (unsigned)(bd[2 * q] >> 32),
                          (unsigned)bd[2 * q + 1], (unsigned)(bd[2 * q + 1] >> 32) };
            *(uint4*)&uni[k][(h << 4) + 2 * (q ^ ksw)] = val;
        }
    }
    __syncthreads();

    // ---- phase 2: merge halves (even threads), normalize, write rel ----
    if (h == 0) {
        u64 A[16], B[16];
        #pragma unroll
        for (int q = 0; q < 8; ++q) {
            const int qp = 2 * (q ^ ksw);
            uint4 va = *(const uint4*)&uni[k][qp];
            uint4 vb = *(const uint4*)&uni[k][16 + qp];
            A[2 * q]     = (u64)va.x | ((u64)va.y << 32);
            A[2 * q + 1] = (u64)va.z | ((u64)va.w << 32);
            B[2 * q]     = (u64)vb.x | ((u64)vb.y << 32);
            B[2 * q + 1] = (u64)vb.z | ((u64)vb.w << 32);
        }
        unsigned maskA = 0;
        #pragma unroll
        for (int i = 0; i < 16; ++i)
            maskA |= (A[i] < B[15 - i]) ? (1u << i) : 0u;   // A[i] in global top-16
        const int cA = __popc(maskA);
        unsigned idxA[16], idxB[16];
        #pragma unroll
        for (int i = 0; i < 16; ++i) {
            idxA[i] = (unsigned)A[i] & 127u;
            idxB[i] = (unsigned)B[i] & 127u;
        }
        float scale = 0.0f;
        #pragma unroll
        for (int i = 0; i < 16; ++i) {
            f32x4 PA = *(const f32x4*)&pts4[idxA[i]][0];
            float dx = PA.x - Q.x, dy = PA.y - Q.y, dz = PA.z - Q.z;
            float nA = sqrtf(dx * dx + dy * dy + dz * dz);
            scale = fmaxf(scale, ((maskA >> i) & 1) ? nA : 0.0f);
            f32x4 PB = *(const f32x4*)&pts4[idxB[i]][0];
            float ex = PB.x - Q.x, ey = PB.y - Q.y, ez = PB.z - Q.z;
            float nB = sqrtf(ex * ex + ey * ey + ez * ez);
            scale = fmaxf(scale, (!((maskA >> (15 - i)) & 1)) ? nB : 0.0f);
        }
        const float inv = 1.0f / fmaxf(scale, 1e-8f);
        float* relf = (float*)&uni[k][0];
        int rowB = cA;
        #pragma unroll
        for (int i = 0; i < 16; ++i) {
            if ((maskA >> i) & 1) {            // selected A's are prefix: row = i
                f32x4 P = *(const f32x4*)&pts4[idxA[i]][0];
                relf[i * 3 + 0] = (P.x - Q.x) * inv;
                relf[i * 3 + 1] = (P.y - Q.y) * inv;
                relf[i * 3 + 2] = (P.z - Q.z) * inv;
            }
            if (!((maskA >> (15 - i)) & 1)) {  // selected B's: rows cA..15
                f32x4 P = *(const f32x4*)&pts4[idxB[i]][0];
                relf[rowB * 3 + 0] = (P.x - Q.x) * inv;
                relf[rowB * 3 + 1] = (P.y - Q.y) * inv;
                relf[rowB * 3 + 2] = (P.z - Q.z) * inv;
                ++rowB;
            }
        }
    }
    __syncthreads();

    // ---- load persistent weight fragments AFTER kNN (caps register pressure) ----
    bf16x8 w2A[4];
    #pragma unroll
    for (int t = 0; t < 4; ++t) {
        const int c = 32 * (t >> 1) + 8 * (ln >> 2) + 4 * (t & 1) + (ln & 3);
        #pragma unroll
        for (int j = 0; j < 8; ++j)
            w2A[t][j] = (__bf16)W2[(g * 8 + j) * 64 + c];
    }
    float b2p[16];
    #pragma unroll
    for (int t = 0; t < 4; ++t)
        #pragma unroll
        for (int r = 0; r < 4; ++r)
            b2p[t * 4 + r] = b2[32 * (t >> 1) + 8 * g + 4 * (t & 1) + r];
    float w1r0[8], w1r1[8], w1r2[8], b1r[8];
    #pragma unroll
    for (int j = 0; j < 8; ++j) {
        const int c = g * 8 + j;
        w1r0[j] = W1[c]; w1r1[j] = W1[32 + c]; w1r2[j] = W1[64 + c]; b1r[j] = b1[c];
    }
    const float b3r0 = b3[(2 * g) * 16 + ln];
    const float b3r1 = b3[(2 * g + 1) * 16 + ln];

    // ---- phase 3: MFMA MLP, 2 points per iteration (shared W3 stream, 2x ILP) ----
    #pragma unroll 1
    for (int i = 0; i < 16; ++i) {
        const int p0 = w * 32 + 2 * i;
        const int p1 = p0 + 1;
        const float* rf0 = (const float*)&uni[p0][0];
        const float* rf1 = (const float*)&uni[p1][0];
        const float r00 = rf0[ln * 3], r01 = rf0[ln * 3 + 1], r02 = rf0[ln * 3 + 2];
        const float r10 = rf1[ln * 3], r11 = rf1[ln * 3 + 1], r12 = rf1[ln * 3 + 2];

        // L1 both points -> B-frag (lane = neighbor), hi/lo split
        bf16x8 a1hi0, a1lo0, a1hi1, a1lo1;
        #pragma unroll
        for (int j = 0; j < 8; ++j) {
            float h0 = fmaf(r02, w1r2[j], fmaf(r01, w1r1[j], fmaf(r00, w1r0[j], b1r[j])));
            h0 = fmaxf(h0, 0.0f);
            __bf16 hh0 = (__bf16)h0;
            a1hi0[j] = hh0; a1lo0[j] = (__bf16)(h0 - (float)hh0);
            float h1v = fmaf(r12, w1r2[j], fmaf(r11, w1r1[j], fmaf(r10, w1r0[j], b1r[j])));
            h1v = fmaxf(h1v, 0.0f);
            __bf16 hh1 = (__bf16)h1v;
            a1hi1[j] = hh1; a1lo1[j] = (__bf16)(h1v - (float)hh1);
        }

        // L2 transposed, both points
        f32x4 c2_0[4], c2_1[4];
        #pragma unroll
        for (int t = 0; t < 4; ++t) {
            f32x4 acc0 = {b2p[t*4+0], b2p[t*4+1], b2p[t*4+2], b2p[t*4+3]};
            f32x4 acc1 = acc0;
            acc0 = MFMA(w2A[t], a1hi0, acc0);
            acc1 = MFMA(w2A[t], a1hi1, acc1);
            acc0 = MFMA(w2A[t], a1lo0, acc0);
            acc1 = MFMA(w2A[t], a1lo1, acc1);
            c2_0[t] = acc0; c2_1[t] = acc1;
        }

        // relu + hi/lo pack into L3 A-frags (sigma renaming)
        bf16x8 h30a, l30a, h30b, l30b;   // point0: kb=0, kb=1
        bf16x8 h31a, l31a, h31b, l31b;   // point1
        #pragma unroll
        for (int j = 0; j < 8; ++j) {
            const int r = j & 3, ta = j >> 2, tb = 2 + (j >> 2);
            float v0a = fmaxf(c2_0[ta][r], 0.0f);
            __bf16 x0a = (__bf16)v0a; h30a[j] = x0a; l30a[j] = (__bf16)(v0a - (float)x0a);
            float v0b = fmaxf(c2_0[tb][r], 0.0f);
            __bf16 x0b = (__bf16)v0b; h30b[j] = x0b; l30b[j] = (__bf16)(v0b - (float)x0b);
            float v1a = fmaxf(c2_1[ta][r], 0.0f);
            __bf16 x1a = (__bf16)v1a; h31a[j] = x1a; l31a[j] = (__bf16)(v1a - (float)x1a);
            float v1b = fmaxf(c2_1[tb][r], 0.0f);
            __bf16 x1b = (__bf16)v1b; h31b[j] = x1b; l31b[j] = (__bf16)(v1b - (float)x1b);
        }

        // L3: 4 steps x 2 tiles, W3 frags read once, used by both points
        float s0_0 = 0.f, s1_0 = 0.f, s0_1 = 0.f, s1_1 = 0.f;
        #pragma unroll
        for (int nn = 0; nn < 4; ++nn) {
            bf16x8 c0a = __builtin_bit_cast(bf16x8, w3lds[nn * 4 + 0][lane]);
            bf16x8 c0b = __builtin_bit_cast(bf16x8, w3lds[nn * 4 + 1][lane]);
            bf16x8 c1a = __builtin_bit_cast(bf16x8, w3lds[nn * 4 + 2][lane]);
            bf16x8 c1b = __builtin_bit_cast(bf16x8, w3lds[nn * 4 + 3][lane]);
            f32x4 a00 = {0,0,0,0}, a01 = {0,0,0,0}, a10 = {0,0,0,0}, a11 = {0,0,0,0};
            a00 = MFMA(h30a, c0a, a00); a00 = MFMA(h30b, c0b, a00);
            a00 = MFMA(l30a, c0a, a00); a00 = MFMA(l30b, c0b, a00);
            a01 = MFMA(h30a, c1a, a01); a01 = MFMA(h30b, c1b, a01);
            a01 = MFMA(l30a, c1a, a01); a01 = MFMA(l30b, c1b, a01);
            a10 = MFMA(h31a, c0a, a10); a10 = MFMA(h31b, c0b, a10);
            a10 = MFMA(l31a, c0a, a10); a10 = MFMA(l31b, c0b, a10);
            a11 = MFMA(h31a, c1a, a11); a11 = MFMA(h31b, c1b, a11);
            a11 = MFMA(l31a, c1a, a11); a11 = MFMA(l31b, c1b, a11);
            float v00 = fmaxf(fmaxf(a00[0], a00[1]), fmaxf(a00[2], a00[3]));
            v00 = fmaxf(v00, __shfl_xor(v00, 16)); v00 = fmaxf(v00, __shfl_xor(v00, 32));
            float v01 = fmaxf(fmaxf(a01[0], a01[1]), fmaxf(a01[2], a01[3]));
            v01 = fmaxf(v01, __shfl_xor(v01, 16)); v01 = fmaxf(v01, __shfl_xor(v01, 32));
            float v10 = fmaxf(fmaxf(a10[0], a10[1]), fmaxf(a10[2], a10[3]));
            v10 = fmaxf(v10, __shfl_xor(v10, 16)); v10 = fmaxf(v10, __shfl_xor(v10, 32));
            float v11 = fmaxf(fmaxf(a11[0], a11[1]), fmaxf(a11[2], a11[3]));
            v11 = fmaxf(v11, __shfl_xor(v11, 16)); v11 = fmaxf(v11, __shfl_xor(v11, 32));
            if (nn == g) { s0_0 = v00; s1_0 = v01; s0_1 = v10; s1_1 = v11; }
        }
        float* o0 = out + ((size_t)(m * 128 + p0) << 7);
        float* o1 = out + ((size_t)(m * 128 + p1) << 7);
        o0[(2 * g) * 16 + ln]     = s0_0 + b3r0;
        o0[(2 * g + 1) * 16 + ln] = s1_0 + b3r1;
        o1[(2 * g) * 16 + ln]     = s0_1 + b3r0;
        o1[(2 * g + 1) * 16 + ln] = s1_1 + b3r1;
    }
}

extern "C" void kernel_launch(void* const* d_in, const int* in_sizes, int n_in,
                              void* d_out, int out_size, void* d_ws, size_t ws_size,
                              hipStream_t stream) {
    const float* windows = (const float*)d_in[0];
    const float* W1 = (const float*)d_in[1];
    const float* b1 = (const float*)d_in[2];
    const float* W2 = (const float*)d_in[3];
    const float* b2 = (const float*)d_in[4];
    const float* W3 = (const float*)d_in[5];
    const float* b3 = (const float*)d_in[6];
    float* out = (float*)d_out;
    hipLaunchKernelGGL(miniemb_kernel, dim3(1024), dim3(256), 0, stream,
                       windows, W1, b1, W2, b2, W3, b3, out);
}